// Round 16
// baseline (239.237 us; speedup 1.0000x reference)
//
#include <hip/hip_runtime.h>

typedef __attribute__((ext_vector_type(4))) float f32x4;
typedef __attribute__((ext_vector_type(8))) short s16x8;

#define DEV static __device__ __forceinline__

typedef __attribute__((address_space(3))) void lds_t;
typedef __attribute__((address_space(1))) void gbl_t;

DEV void gload_lds16(const void* g, void* l) {
    __builtin_amdgcn_global_load_lds((gbl_t*)g, (lds_t*)l, 16, 0, 0);
}

DEV ushort f2bf(float f) {
    unsigned u = __float_as_uint(f);
    u += 0x7fffu + ((u >> 16) & 1u);   // round-to-nearest-even
    return (ushort)(u >> 16);
}
DEV float bf2f(ushort h) { return __uint_as_float(((unsigned)h) << 16); }

// raw barrier with compiler+scheduler fences (no vmcnt(0) drain, unlike __syncthreads)
#define FULLBAR() do {                              \
    __builtin_amdgcn_sched_barrier(0);              \
    asm volatile("" ::: "memory");                  \
    __builtin_amdgcn_s_barrier();                   \
    asm volatile("" ::: "memory");                  \
    __builtin_amdgcn_sched_barrier(0);              \
} while (0)

#define WAITVM(n) asm volatile("s_waitcnt vmcnt(" #n ")" ::: "memory")
#define LGKM0() asm volatile("s_waitcnt lgkmcnt(0)" ::: "memory")

// ------------- unified prep: x-pack + weight transposes/packs, one dispatch --------------
// bx <  64 : trans_pack_kv -> wkvT [2048][1024] (k/v cols interleaved [k_h,v_h,k_h+1,v_h+1]/256)
// bx <  96 : trans_pack woutT [1024][1024]
// bx < 128 : pack_wq -> wqb [c][1024] (q cols of w_qkv, row-major)
// bx >=128 : pack x fp32 -> bf16 xb [16384][1024]
__global__ void prep_k(const float* __restrict__ x, const float* __restrict__ wqkv,
                       const float* __restrict__ wout,
                       ushort* __restrict__ xb, ushort* __restrict__ wqb,
                       ushort* __restrict__ wkvT, ushort* __restrict__ woutT) {
    __shared__ float tile[32][33];
    const int bx = blockIdx.x, by = blockIdx.y;
    const int tx = threadIdx.x, ty = threadIdx.y;   // (32, 8)
    if (bx < 64) {
        int bxo = bx * 32, byr = by * 32;
        int blk = bxo >> 8, grp = (bxo >> 6) & 3, d0 = bxo & 63;
        int h = blk * 2 + (grp >> 1);
        int src = 1024 + (grp & 1) * 1024 + h * 64 + d0;
#pragma unroll
        for (int i = 0; i < 32; i += 8)
            tile[ty + i][tx] = wqkv[(size_t)(byr + ty + i) * 3072 + src + tx];
        __syncthreads();
#pragma unroll
        for (int i = 0; i < 32; i += 8)
            wkvT[(size_t)(bxo + ty + i) * 1024 + byr + tx] = f2bf(tile[tx][ty + i]);
    } else if (bx < 96) {
        int bxo = (bx - 64) * 32, byr = by * 32;
#pragma unroll
        for (int i = 0; i < 32; i += 8)
            tile[ty + i][tx] = wout[(size_t)(byr + ty + i) * 1024 + bxo + tx];
        __syncthreads();
#pragma unroll
        for (int i = 0; i < 32; i += 8)
            woutT[(size_t)(bxo + ty + i) * 1024 + byr + tx] = f2bf(tile[tx][ty + i]);
    } else if (bx < 128) {
        int t = ty * 32 + tx;
        int i = ((bx - 96) * 32 + by) * 256 + t;    // 0 .. 262143
        int r = i >> 8, c4 = i & 255;
        float4 v = *reinterpret_cast<const float4*>(wqkv + (size_t)r * 3072 + c4 * 4);
        ushort4 u;
        u.x = f2bf(v.x); u.y = f2bf(v.y); u.z = f2bf(v.z); u.w = f2bf(v.w);
        *reinterpret_cast<ushort4*>(wqb + (size_t)r * 1024 + c4 * 4) = u;
    } else {
        int t = ty * 32 + tx;
        int i = ((bx - 128) * 32 + by) * 256 + t;   // 0 .. 4194303 float4-groups
        float4 v = reinterpret_cast<const float4*>(x)[i];
        ushort4 u;
        u.x = f2bf(v.x); u.y = f2bf(v.y); u.z = f2bf(v.z); u.w = f2bf(v.w);
        reinterpret_cast<ushort4*>(xb)[i] = u;
    }
}

// ---------------- main GEMM: C[M][Nn] = A[M][K=1024](bf16) * Bt[Nn][1024]^T (bf16), fp32 acc --------
// 256x256 block tile, 512 threads (8 waves 2M x 4N), per-wave 128x64, BK=64 (16 K-tiles),
// 2-slot LDS double buffer (128 KB), barrier-lean schedule (2 barriers/K-tile, counted vmcnt).
// MODE 0: B = interleaved wkvT ([k_h,v_h,k_h+1,v_h+1] per 256 cols). Epilogue: fused per-head
//   LayerNorm -> LN'd k,v tiles into (dead) staging LDS [4 grp][64 c][256 n] (granule-XOR,
//   ushort4-vectorized writes) -> partial scores S_h = k^T v over this block's 256 n ->
//   fp32 atomicAdd into sc[bh][d][e].  NO k/v global round-trip.
// MODE 1: add bias, write fp32 to outf[M][Nn]; Bt selected per-b via b_stride (b = m0>>12).
template <int MODE>
__global__ __launch_bounds__(512, 1) void gemm_bt_k(
    const ushort* __restrict__ A, const ushort* __restrict__ Bt,
    int Nn, size_t b_stride,
    float* __restrict__ scp,
    const float* __restrict__ gk, const float* __restrict__ bk,
    const float* __restrict__ gv, const float* __restrict__ bv,
    const float* __restrict__ bias, float* __restrict__ outf)
{
    // 2 slots x (A 256x64 + B 256x64) ushorts = 128 KB; MODE-0 kv buffer overlays exactly.
    __shared__ __align__(16) ushort SH[65536];
    const int t = threadIdx.x;
    const int w = t >> 6, lane = t & 63;
    const int wr = w >> 2, wc = w & 3;          // wave grid 2M x 4N
    const int lrow = lane & 15, kh = lane >> 4;

    // bijective XCD-chunked swizzle (grid total % 8 == 0)
    int bid = blockIdx.y * gridDim.x + blockIdx.x;
    int C8 = (gridDim.x * gridDim.y) >> 3;
    int nid = (bid & 7) * C8 + (bid >> 3);
    int n0 = (nid % gridDim.x) * 256;
    int m0 = (nid / gridDim.x) * 256;

    const ushort* Bte = (MODE == 1) ? Bt + (size_t)(m0 >> 12) * b_stride : Bt;

    // staging: half h, call c covers rows h*128 + c*64 + w*8 + (lane>>3); source pre-swizzled
    const int srow8 = w * 8 + (lane >> 3);
    const int scol = ((lane & 7) ^ ((lane >> 3) & 7)) * 8;

    // read granule offsets (ushorts): g' = (kk*4+kh) ^ (lrow&7), per-lane constants
    const int g0 = ((kh) ^ (lrow & 7)) * 8;
    const int g1 = ((4 + kh) ^ (lrow & 7)) * 8;

    f32x4 acc[8][4] = {};
    s16x8 bfr[4][2];
    s16x8 af[8];

    auto STAGE_A = [&](int kt, int s, int h) {
        ushort* As = SH + s * 32768;
        const ushort* Ag = A + (size_t)(m0 + h * 128 + srow8) * 1024 + kt * 64 + scol;
        gload_lds16(Ag,                     As + (h * 128 + w * 8) * 64);
        gload_lds16(Ag + (size_t)64 * 1024, As + (h * 128 + 64 + w * 8) * 64);
    };
    auto STAGE_B = [&](int kt, int s, int h) {
        ushort* Bs = SH + s * 32768 + 16384;
        const ushort* Bg = Bte + (size_t)(n0 + h * 128 + srow8) * 1024 + kt * 64 + scol;
        gload_lds16(Bg,                     Bs + (h * 128 + w * 8) * 64);
        gload_lds16(Bg + (size_t)64 * 1024, Bs + (h * 128 + 64 + w * 8) * 64);
    };

    // prologue: tile0 (A+B) + tile1's B halves = 12 loads
    STAGE_A(0, 0, 0); STAGE_A(0, 0, 1);
    STAGE_B(0, 0, 0); STAGE_B(0, 0, 1);
    STAGE_B(1, 1, 0); STAGE_B(1, 1, 1);

    for (int kt = 0; kt < 16; ++kt) {
        const int p = kt & 1, q = p ^ 1;
        const ushort* As = SH + p * 32768;
        const ushort* Bs = As + 16384;

        if (kt < 15) { WAITVM(4); } else { WAITVM(0); }
        FULLBAR();                          // tile kt fully landed for all waves

        // issue all B reads (both kk) and A kk0 reads; stage A(kt+1) into other buf
#pragma unroll
        for (int ni = 0; ni < 4; ni++) {
            const int r = (wc * 64 + ni * 16 + lrow) * 64;
            bfr[ni][0] = *reinterpret_cast<const s16x8*>(&Bs[r + g0]);
            bfr[ni][1] = *reinterpret_cast<const s16x8*>(&Bs[r + g1]);
        }
#pragma unroll
        for (int mi = 0; mi < 8; mi++)
            af[mi] = *reinterpret_cast<const s16x8*>(&As[(wr * 128 + mi * 16 + lrow) * 64 + g0]);
        if (kt + 1 < 16) { STAGE_A(kt + 1, q, 0); STAGE_A(kt + 1, q, 1); }

        __builtin_amdgcn_s_setprio(1);
#pragma unroll
        for (int mi = 0; mi < 8; mi++)
#pragma unroll
            for (int ni = 0; ni < 4; ni++)
                acc[mi][ni] = __builtin_amdgcn_mfma_f32_16x16x32_bf16(af[mi], bfr[ni][0], acc[mi][ni], 0, 0, 0);
        __builtin_amdgcn_s_setprio(0);

        LGKM0();                            // all my ds_reads (incl. bfr[..][1]) complete
        FULLBAR();                          // => all waves' B(kt) reads complete

        // stage B(kt+2) into same buf's B region (now provably dead); A kk1 reads
        if (kt + 2 < 16) { STAGE_B(kt + 2, p, 0); STAGE_B(kt + 2, p, 1); }
#pragma unroll
        for (int mi = 0; mi < 8; mi++)
            af[mi] = *reinterpret_cast<const s16x8*>(&As[(wr * 128 + mi * 16 + lrow) * 64 + g1]);

        __builtin_amdgcn_s_setprio(1);
#pragma unroll
        for (int mi = 0; mi < 8; mi++)
#pragma unroll
            for (int ni = 0; ni < 4; ni++)
                acc[mi][ni] = __builtin_amdgcn_mfma_f32_16x16x32_bf16(af[mi], bfr[ni][1], acc[mi][ni], 0, 0, 0);
        __builtin_amdgcn_s_setprio(0);
    }

    // C/D layout (verified m89): col = lane&15, row = (lane>>4)*4 + reg
    if (MODE == 0) {
        // this wave's 64-col group: n0 block covers heads 2i, 2i+1 as [k,v,k,v]
        const int i_nb = n0 >> 8;
        const int h = i_nb * 2 + (wc >> 1);
        const int is_k = ((wc & 1) == 0);
        const float* g  = is_k ? gk : gv;
        const float* bb = is_k ? bk : bv;
        float gr[4], br[4];
#pragma unroll
        for (int ni = 0; ni < 4; ni++) {
            gr[ni] = g[h * 64 + ni * 16 + lrow];
            br[ni] = bb[h * 64 + ni * 16 + lrow];
        }
        __syncthreads();                    // staging LDS dead for ALL waves; kv buffer overlays
        // write LN'd values into group wc: [64 c][256 n], 8-ushort granules XOR'd by (c&31).
        // For fixed (mi,ni) the 4 j-values are contiguous ushorts (n&7 = (kh&1)*4+j) -> ushort4.
        ushort* kvl = SH + wc * 16384;
#pragma unroll
        for (int mi = 0; mi < 8; mi++) {
            float muA[4], invA[4];
#pragma unroll
            for (int j = 0; j < 4; j++) {
                float s = acc[mi][0][j] + acc[mi][1][j] + acc[mi][2][j] + acc[mi][3][j];
                s += __shfl_xor(s, 1, 64);
                s += __shfl_xor(s, 2, 64);
                s += __shfl_xor(s, 4, 64);
                s += __shfl_xor(s, 8, 64);
                float mu = s * (1.f / 64.f);
                float t2 = 0.f;
#pragma unroll
                for (int ni = 0; ni < 4; ni++) {
                    float dd = acc[mi][ni][j] - mu;
                    t2 += dd * dd;
                }
                t2 += __shfl_xor(t2, 1, 64);
                t2 += __shfl_xor(t2, 2, 64);
                t2 += __shfl_xor(t2, 4, 64);
                t2 += __shfl_xor(t2, 8, 64);
                muA[j] = mu;
                invA[j] = rsqrtf(t2 * (1.f / 64.f) + 1e-5f);
            }
            const int nbase = wr * 128 + mi * 16 + kh * 4;   // nbase%4==0; n>>3 const over j
            const int gnb = nbase >> 3;
#pragma unroll
            for (int ni = 0; ni < 4; ni++) {
                ushort4 o;
                o.x = f2bf((acc[mi][ni][0] - muA[0]) * invA[0] * gr[ni] + br[ni]);
                o.y = f2bf((acc[mi][ni][1] - muA[1]) * invA[1] * gr[ni] + br[ni]);
                o.z = f2bf((acc[mi][ni][2] - muA[2]) * invA[2] * gr[ni] + br[ni]);
                o.w = f2bf((acc[mi][ni][3] - muA[3]) * invA[3] * gr[ni] + br[ni]);
                const int c = ni * 16 + lrow;
                const int gn = gnb ^ (c & 31);
                *reinterpret_cast<ushort4*>(&kvl[c * 256 + gn * 8 + (kh & 1) * 4]) = o;
            }
        }
        __syncthreads();
        // partial scores: wave w -> local head hp = w>>2, mi-tile T = w&3.
        // S[d][e] = sum_n k[c=d][n] * v[c=e][n] over this block's 256 n (8 K-steps of 32).
        const int hp = w >> 2, T = w & 3;
        const ushort* Ak = SH + (hp * 2) * 16384;
        const ushort* Bv = SH + (hp * 2 + 1) * 16384;
        const int arow = T * 16 + lrow;
        f32x4 sacc[4] = {};
#pragma unroll
        for (int ks = 0; ks < 8; ++ks) {
            const int gnr = ks * 4 + kh;
            s16x8 afk = *reinterpret_cast<const s16x8*>(
                &Ak[arow * 256 + ((gnr ^ (arow & 31)) * 8)]);
#pragma unroll
            for (int ni = 0; ni < 4; ni++) {
                const int erow = ni * 16 + lrow;
                s16x8 bfv = *reinterpret_cast<const s16x8*>(
                    &Bv[erow * 256 + ((gnr ^ (erow & 31)) * 8)]);
                sacc[ni] = __builtin_amdgcn_mfma_f32_16x16x32_bf16(afk, bfv, sacc[ni], 0, 0, 0);
            }
        }
        const int bh = (m0 >> 12) * 16 + i_nb * 2 + hp;
        float* scb = scp + (size_t)bh * 4096;
        const float scale = 1.f / 4096.f;
#pragma unroll
        for (int ni = 0; ni < 4; ni++)
#pragma unroll
            for (int j = 0; j < 4; j++) {
                const int d = T * 16 + kh * 4 + j;
                const int e = ni * 16 + lrow;
                atomicAdd(&scb[d * 64 + e], sacc[ni][j] * scale);
            }
    } else {
#pragma unroll
        for (int mi = 0; mi < 8; mi++)
#pragma unroll
            for (int ni = 0; ni < 4; ni++) {
                int e = n0 + wc * 64 + ni * 16 + lrow;
                float bv2 = bias[e];
#pragma unroll
                for (int j = 0; j < 4; j++) {
                    int m = m0 + wr * 128 + mi * 16 + kh * 4 + j;
                    outf[(size_t)m * Nn + e] = acc[mi][ni][j] + bv2;
                }
            }
    }
}

// ---------- merged wprime+fold: fT[b*1024+f][c] = sum_h sum_d T_h[f][d] * wqb[c][h*64+d],
//            T_h[f][d] = sum_e woutT[f][h*64+e] * sc[b*16+h][d*64+e]   (bf16 T, fp32 acc)
// grid (8 c-tiles, 32 (b,f)-tiles), 512 threads (8 waves, wave w owns f-rows [w*16, w*16+16)).
__global__ __launch_bounds__(512) void wfold_k(const float* __restrict__ sc,
                                               const ushort* __restrict__ woutT,
                                               const ushort* __restrict__ wqb,
                                               ushort* __restrict__ fT)
{
    __shared__ ushort Sl[64 * 72];      // S_bh bf16 [d][e], pitch 72
    __shared__ ushort Tl[128 * 72];     // T_h bf16 [f_loc][d], pitch 72
    const int t = threadIdx.x;
    const int w = t >> 6, lane = t & 63;
    const int lrow = lane & 15, kh = lane >> 4;
    const int c0 = blockIdx.x * 128;
    const int m0 = blockIdx.y * 128;            // flat m: b = m0>>10, f0 = m0&1023
    const int b = m0 >> 10;

    f32x4 facc[8] = {};
    const int Frow = m0 + w * 16 + lrow;        // woutT row (f0 + f_loc) ; m0&1023 + 127 < 1024

    for (int h = 0; h < 16; ++h) {
        const float* sb = sc + ((size_t)(b * 16 + h)) * 4096;
        // load S_bh -> bf16 LDS [d][e] (each thread: 8 contiguous)
#pragma unroll
        for (int ii = 0; ii < 8; ++ii) {
            int idx = t * 8 + ii;
            Sl[(idx >> 6) * 72 + (idx & 63)] = f2bf(sb[idx]);
        }
        __syncthreads();                        // BAR1: Sl ready; prev-h Tl reads all consumed
        // phase T: T[f][d] = sum_e woutT[f][h*64+e] * S[d][e]; wave w -> f rows w*16..+16
        {
            f32x4 tacc[4] = {};
            s16x8 a0 = *reinterpret_cast<const s16x8*>(
                woutT + (size_t)(Frow & 1023) * 1024 + h * 64 + kh * 8);
            s16x8 a1 = *reinterpret_cast<const s16x8*>(
                woutT + (size_t)(Frow & 1023) * 1024 + h * 64 + 32 + kh * 8);
#pragma unroll
            for (int ni = 0; ni < 4; ni++) {
                const ushort* srow = &Sl[(ni * 16 + lrow) * 72];
                s16x8 b0 = *reinterpret_cast<const s16x8*>(srow + kh * 8);
                s16x8 b1 = *reinterpret_cast<const s16x8*>(srow + 32 + kh * 8);
                tacc[ni] = __builtin_amdgcn_mfma_f32_16x16x32_bf16(a0, b0, tacc[ni], 0, 0, 0);
                tacc[ni] = __builtin_amdgcn_mfma_f32_16x16x32_bf16(a1, b1, tacc[ni], 0, 0, 0);
            }
            // C layout: f_loc = w*16 + kh*4 + j, d = ni*16 + lrow
#pragma unroll
            for (int ni = 0; ni < 4; ni++)
#pragma unroll
                for (int j = 0; j < 4; j++)
                    Tl[(w * 16 + kh * 4 + j) * 72 + ni * 16 + lrow] = f2bf(tacc[ni][j]);
        }
        __syncthreads();                        // BAR2: Tl ready
        // phase B: facc[f][c] += sum_d T[f][d] * wqb[c0+c][h*64+d]
        {
            s16x8 a0 = *reinterpret_cast<const s16x8*>(&Tl[(w * 16 + lrow) * 72 + kh * 8]);
            s16x8 a1 = *reinterpret_cast<const s16x8*>(&Tl[(w * 16 + lrow) * 72 + 32 + kh * 8]);
#pragma unroll
            for (int ni = 0; ni < 8; ni++) {
                const ushort* qrow = wqb + (size_t)(c0 + ni * 16 + lrow) * 1024 + h * 64;
                s16x8 b0 = *reinterpret_cast<const s16x8*>(qrow + kh * 8);
                s16x8 b1 = *reinterpret_cast<const s16x8*>(qrow + 32 + kh * 8);
                facc[ni] = __builtin_amdgcn_mfma_f32_16x16x32_bf16(a0, b0, facc[ni], 0, 0, 0);
                facc[ni] = __builtin_amdgcn_mfma_f32_16x16x32_bf16(a1, b1, facc[ni], 0, 0, 0);
            }
        }
        // next h's Sl write is gated by its BAR1? No: Sl writes precede BAR1. Safe because
        // this h's Sl reads (phase T) completed before BAR2, which everyone passed.
        __syncthreads();                        // BAR3: protect Tl until all waves' phase-B reads done
    }
    // write fT tile: f = m0 + w*16 + kh*4 + j, c = c0 + ni*16 + lrow
#pragma unroll
    for (int ni = 0; ni < 8; ni++)
#pragma unroll
        for (int j = 0; j < 4; j++)
            fT[(size_t)(m0 + w * 16 + kh * 4 + j) * 1024 + c0 + ni * 16 + lrow] =
                f2bf(facc[ni][j]);
}

extern "C" void kernel_launch(void* const* d_in, const int* in_sizes, int n_in,
                              void* d_out, int out_size, void* d_ws, size_t ws_size,
                              hipStream_t stream)
{
    const float* x       = (const float*)d_in[0];
    const float* w_qkv   = (const float*)d_in[1];
    const float* gamma_k = (const float*)d_in[2];
    const float* beta_k  = (const float*)d_in[3];
    const float* gamma_v = (const float*)d_in[4];
    const float* beta_v  = (const float*)d_in[5];
    const float* w_out   = (const float*)d_in[6];
    const float* b_out   = (const float*)d_in[7];
    float* out = (float*)d_out;

    char* ws = (char*)d_ws;
    const size_t MB = 1024 * 1024;
    ushort* xb    = (ushort*)(ws);               // 32MB [m][1024] (alive through GEMM2)
    ushort* wkvT  = (ushort*)(ws + 32 * MB);     // 4MB  [2048][1024] interleaved k/v transposed
    ushort* woutT = (ushort*)(ws + 38 * MB);     // 2MB  [1024][1024]
    ushort* wqb   = (ushort*)(ws + 40 * MB);     // 2MB  [c][1024] (q cols of w_qkv, row-major)
    float*  sc    = (float*)(ws + 48 * MB);      // 1MB  [bh][d][e]
    ushort* fT    = (ushort*)(ws + 64 * MB);     // 8MB  [b][f][c] == flat [4096][1024]

    hipMemsetAsync(sc, 0, 64 * 4096 * sizeof(float), stream);
    prep_k<<<dim3(640, 32), dim3(32, 8), 0, stream>>>(x, w_qkv, w_out, xb, wqb, wkvT, woutT);
    // GEMM1: k,v + fused LN + fused partial-scores (atomics into sc). No k/v round-trip.
    gemm_bt_k<0><<<dim3(8, 64), 512, 0, stream>>>(xb, wkvT, 2048, 0,
                                                  sc,
                                                  gamma_k, beta_k, gamma_v, beta_v,
                                                  nullptr, nullptr);
    // merged wprime+fold: fT[m][c] directly from sc
    wfold_k<<<dim3(8, 32), 512, 0, stream>>>(sc, woutT, wqb, fT);
    // GEMM2: out = xb · fT(b)^T + bias
    gemm_bt_k<1><<<dim3(4, 64), 512, 0, stream>>>(xb, fT, 1024, (size_t)1048576,
                                                  nullptr,
                                                  nullptr, nullptr, nullptr, nullptr,
                                                  b_out, out);
}

// Round 17
// 192.647 us; speedup vs baseline: 1.2418x; 1.2418x over previous
//
#include <hip/hip_runtime.h>

typedef __attribute__((ext_vector_type(4))) float f32x4;
typedef __attribute__((ext_vector_type(8))) short s16x8;

#define DEV static __device__ __forceinline__

typedef __attribute__((address_space(3))) void lds_t;
typedef __attribute__((address_space(1))) void gbl_t;

DEV void gload_lds16(const void* g, void* l) {
    __builtin_amdgcn_global_load_lds((gbl_t*)g, (lds_t*)l, 16, 0, 0);
}

DEV ushort f2bf(float f) {
    unsigned u = __float_as_uint(f);
    u += 0x7fffu + ((u >> 16) & 1u);   // round-to-nearest-even
    return (ushort)(u >> 16);
}
DEV float bf2f(ushort h) { return __uint_as_float(((unsigned)h) << 16); }

// raw barrier with compiler+scheduler fences (no vmcnt(0) drain, unlike __syncthreads)
#define FULLBAR() do {                              \
    __builtin_amdgcn_sched_barrier(0);              \
    asm volatile("" ::: "memory");                  \
    __builtin_amdgcn_s_barrier();                   \
    asm volatile("" ::: "memory");                  \
    __builtin_amdgcn_sched_barrier(0);              \
} while (0)

#define WAITVM(n) asm volatile("s_waitcnt vmcnt(" #n ")" ::: "memory")
#define LGKM0() asm volatile("s_waitcnt lgkmcnt(0)" ::: "memory")

// ------------- unified prep: x-pack + weight transposes/packs, one dispatch --------------
// bx <  64 : trans_pack_kv -> wkvT [2048][1024] (k/v cols interleaved [k_h,v_h,k_h+1,v_h+1]/256)
// bx <  96 : trans_pack woutT [1024][1024]
// bx < 128 : pack_wq -> wqb [c][1024] (q cols of w_qkv, row-major)
// bx >=128 : pack x fp32 -> bf16 xb [16384][1024]
__global__ void prep_k(const float* __restrict__ x, const float* __restrict__ wqkv,
                       const float* __restrict__ wout,
                       ushort* __restrict__ xb, ushort* __restrict__ wqb,
                       ushort* __restrict__ wkvT, ushort* __restrict__ woutT) {
    __shared__ float tile[32][33];
    const int bx = blockIdx.x, by = blockIdx.y;
    const int tx = threadIdx.x, ty = threadIdx.y;   // (32, 8)
    if (bx < 64) {
        int bxo = bx * 32, byr = by * 32;
        int blk = bxo >> 8, grp = (bxo >> 6) & 3, d0 = bxo & 63;
        int h = blk * 2 + (grp >> 1);
        int src = 1024 + (grp & 1) * 1024 + h * 64 + d0;
#pragma unroll
        for (int i = 0; i < 32; i += 8)
            tile[ty + i][tx] = wqkv[(size_t)(byr + ty + i) * 3072 + src + tx];
        __syncthreads();
#pragma unroll
        for (int i = 0; i < 32; i += 8)
            wkvT[(size_t)(bxo + ty + i) * 1024 + byr + tx] = f2bf(tile[tx][ty + i]);
    } else if (bx < 96) {
        int bxo = (bx - 64) * 32, byr = by * 32;
#pragma unroll
        for (int i = 0; i < 32; i += 8)
            tile[ty + i][tx] = wout[(size_t)(byr + ty + i) * 1024 + bxo + tx];
        __syncthreads();
#pragma unroll
        for (int i = 0; i < 32; i += 8)
            woutT[(size_t)(bxo + ty + i) * 1024 + byr + tx] = f2bf(tile[tx][ty + i]);
    } else if (bx < 128) {
        int t = ty * 32 + tx;
        int i = ((bx - 96) * 32 + by) * 256 + t;    // 0 .. 262143
        int r = i >> 8, c4 = i & 255;
        float4 v = *reinterpret_cast<const float4*>(wqkv + (size_t)r * 3072 + c4 * 4);
        ushort4 u;
        u.x = f2bf(v.x); u.y = f2bf(v.y); u.z = f2bf(v.z); u.w = f2bf(v.w);
        *reinterpret_cast<ushort4*>(wqb + (size_t)r * 1024 + c4 * 4) = u;
    } else {
        int t = ty * 32 + tx;
        int i = ((bx - 128) * 32 + by) * 256 + t;   // 0 .. 4194303 float4-groups
        float4 v = reinterpret_cast<const float4*>(x)[i];
        ushort4 u;
        u.x = f2bf(v.x); u.y = f2bf(v.y); u.z = f2bf(v.z); u.w = f2bf(v.w);
        reinterpret_cast<ushort4*>(xb)[i] = u;
    }
}

// ---------------- main GEMM: C[M][Nn] = A[M][K=1024](bf16) * Bt[Nn][1024]^T (bf16), fp32 acc --------
// 256x256 block tile, 512 threads (8 waves 2M x 4N), per-wave 128x64, BK=64 (16 K-tiles),
// 2-slot LDS double buffer (128 KB), barrier-lean schedule (2 barriers/K-tile, counted vmcnt).
// MODE 0: B = interleaved wkvT ([k_h,v_h,k_h+1,v_h+1] per 256 cols). Epilogue: fused per-head
//   LayerNorm -> LN'd k,v tiles into (dead) staging LDS [4 grp][64 c][256 n] (granule-XOR,
//   ushort4-vectorized writes) -> partial scores S_h = k^T v over this block's 256 n ->
//   fp32 atomicAdd into sc[bh][d][e].  NO k/v global round-trip.
// MODE 1: add bias, write fp32 to outf[M][Nn]; Bt selected per-b via b_stride (b = m0>>12).
template <int MODE>
__global__ __launch_bounds__(512, 1) void gemm_bt_k(
    const ushort* __restrict__ A, const ushort* __restrict__ Bt,
    int Nn, size_t b_stride,
    float* __restrict__ scp,
    const float* __restrict__ gk, const float* __restrict__ bk,
    const float* __restrict__ gv, const float* __restrict__ bv,
    const float* __restrict__ bias, float* __restrict__ outf)
{
    // 2 slots x (A 256x64 + B 256x64) ushorts = 128 KB; MODE-0 kv buffer overlays exactly.
    __shared__ __align__(16) ushort SH[65536];
    const int t = threadIdx.x;
    const int w = t >> 6, lane = t & 63;
    const int wr = w >> 2, wc = w & 3;          // wave grid 2M x 4N
    const int lrow = lane & 15, kh = lane >> 4;

    // bijective XCD-chunked swizzle (grid total % 8 == 0)
    int bid = blockIdx.y * gridDim.x + blockIdx.x;
    int C8 = (gridDim.x * gridDim.y) >> 3;
    int nid = (bid & 7) * C8 + (bid >> 3);
    int n0 = (nid % gridDim.x) * 256;
    int m0 = (nid / gridDim.x) * 256;

    const ushort* Bte = (MODE == 1) ? Bt + (size_t)(m0 >> 12) * b_stride : Bt;

    // staging: half h, call c covers rows h*128 + c*64 + w*8 + (lane>>3); source pre-swizzled
    const int srow8 = w * 8 + (lane >> 3);
    const int scol = ((lane & 7) ^ ((lane >> 3) & 7)) * 8;

    // read granule offsets (ushorts): g' = (kk*4+kh) ^ (lrow&7), per-lane constants
    const int g0 = ((kh) ^ (lrow & 7)) * 8;
    const int g1 = ((4 + kh) ^ (lrow & 7)) * 8;

    f32x4 acc[8][4] = {};
    s16x8 bfr[4][2];
    s16x8 af[8];

    auto STAGE_A = [&](int kt, int s, int h) {
        ushort* As = SH + s * 32768;
        const ushort* Ag = A + (size_t)(m0 + h * 128 + srow8) * 1024 + kt * 64 + scol;
        gload_lds16(Ag,                     As + (h * 128 + w * 8) * 64);
        gload_lds16(Ag + (size_t)64 * 1024, As + (h * 128 + 64 + w * 8) * 64);
    };
    auto STAGE_B = [&](int kt, int s, int h) {
        ushort* Bs = SH + s * 32768 + 16384;
        const ushort* Bg = Bte + (size_t)(n0 + h * 128 + srow8) * 1024 + kt * 64 + scol;
        gload_lds16(Bg,                     Bs + (h * 128 + w * 8) * 64);
        gload_lds16(Bg + (size_t)64 * 1024, Bs + (h * 128 + 64 + w * 8) * 64);
    };

    // prologue: tile0 (A+B) + tile1's B halves = 12 loads
    STAGE_A(0, 0, 0); STAGE_A(0, 0, 1);
    STAGE_B(0, 0, 0); STAGE_B(0, 0, 1);
    STAGE_B(1, 1, 0); STAGE_B(1, 1, 1);

    for (int kt = 0; kt < 16; ++kt) {
        const int p = kt & 1, q = p ^ 1;
        const ushort* As = SH + p * 32768;
        const ushort* Bs = As + 16384;

        if (kt < 15) { WAITVM(4); } else { WAITVM(0); }
        FULLBAR();                          // tile kt fully landed for all waves

        // issue all B reads (both kk) and A kk0 reads; stage A(kt+1) into other buf
#pragma unroll
        for (int ni = 0; ni < 4; ni++) {
            const int r = (wc * 64 + ni * 16 + lrow) * 64;
            bfr[ni][0] = *reinterpret_cast<const s16x8*>(&Bs[r + g0]);
            bfr[ni][1] = *reinterpret_cast<const s16x8*>(&Bs[r + g1]);
        }
#pragma unroll
        for (int mi = 0; mi < 8; mi++)
            af[mi] = *reinterpret_cast<const s16x8*>(&As[(wr * 128 + mi * 16 + lrow) * 64 + g0]);
        if (kt + 1 < 16) { STAGE_A(kt + 1, q, 0); STAGE_A(kt + 1, q, 1); }

        __builtin_amdgcn_s_setprio(1);
#pragma unroll
        for (int mi = 0; mi < 8; mi++)
#pragma unroll
            for (int ni = 0; ni < 4; ni++)
                acc[mi][ni] = __builtin_amdgcn_mfma_f32_16x16x32_bf16(af[mi], bfr[ni][0], acc[mi][ni], 0, 0, 0);
        __builtin_amdgcn_s_setprio(0);

        LGKM0();                            // all my ds_reads (incl. bfr[..][1]) complete
        FULLBAR();                          // => all waves' B(kt) reads complete

        // stage B(kt+2) into same buf's B region (now provably dead); A kk1 reads
        if (kt + 2 < 16) { STAGE_B(kt + 2, p, 0); STAGE_B(kt + 2, p, 1); }
#pragma unroll
        for (int mi = 0; mi < 8; mi++)
            af[mi] = *reinterpret_cast<const s16x8*>(&As[(wr * 128 + mi * 16 + lrow) * 64 + g1]);

        __builtin_amdgcn_s_setprio(1);
#pragma unroll
        for (int mi = 0; mi < 8; mi++)
#pragma unroll
            for (int ni = 0; ni < 4; ni++)
                acc[mi][ni] = __builtin_amdgcn_mfma_f32_16x16x32_bf16(af[mi], bfr[ni][1], acc[mi][ni], 0, 0, 0);
        __builtin_amdgcn_s_setprio(0);
    }

    // C/D layout (verified m89): col = lane&15, row = (lane>>4)*4 + reg
    if (MODE == 0) {
        // this wave's 64-col group: n0 block covers heads 2i, 2i+1 as [k,v,k,v]
        const int i_nb = n0 >> 8;
        const int h = i_nb * 2 + (wc >> 1);
        const int is_k = ((wc & 1) == 0);
        const float* g  = is_k ? gk : gv;
        const float* bb = is_k ? bk : bv;
        float gr[4], br[4];
#pragma unroll
        for (int ni = 0; ni < 4; ni++) {
            gr[ni] = g[h * 64 + ni * 16 + lrow];
            br[ni] = bb[h * 64 + ni * 16 + lrow];
        }
        __syncthreads();                    // staging LDS dead for ALL waves; kv buffer overlays
        // write LN'd values into group wc: [64 c][256 n], 8-ushort granules XOR'd by (c&31).
        // For fixed (mi,ni) the 4 j-values are contiguous ushorts (n&7 = (kh&1)*4+j) -> ushort4.
        ushort* kvl = SH + wc * 16384;
#pragma unroll
        for (int mi = 0; mi < 8; mi++) {
            float muA[4], invA[4];
#pragma unroll
            for (int j = 0; j < 4; j++) {
                float s = acc[mi][0][j] + acc[mi][1][j] + acc[mi][2][j] + acc[mi][3][j];
                s += __shfl_xor(s, 1, 64);
                s += __shfl_xor(s, 2, 64);
                s += __shfl_xor(s, 4, 64);
                s += __shfl_xor(s, 8, 64);
                float mu = s * (1.f / 64.f);
                float t2 = 0.f;
#pragma unroll
                for (int ni = 0; ni < 4; ni++) {
                    float dd = acc[mi][ni][j] - mu;
                    t2 += dd * dd;
                }
                t2 += __shfl_xor(t2, 1, 64);
                t2 += __shfl_xor(t2, 2, 64);
                t2 += __shfl_xor(t2, 4, 64);
                t2 += __shfl_xor(t2, 8, 64);
                muA[j] = mu;
                invA[j] = rsqrtf(t2 * (1.f / 64.f) + 1e-5f);
            }
            const int nbase = wr * 128 + mi * 16 + kh * 4;   // nbase%4==0; n>>3 const over j
            const int gnb = nbase >> 3;
#pragma unroll
            for (int ni = 0; ni < 4; ni++) {
                ushort4 o;
                o.x = f2bf((acc[mi][ni][0] - muA[0]) * invA[0] * gr[ni] + br[ni]);
                o.y = f2bf((acc[mi][ni][1] - muA[1]) * invA[1] * gr[ni] + br[ni]);
                o.z = f2bf((acc[mi][ni][2] - muA[2]) * invA[2] * gr[ni] + br[ni]);
                o.w = f2bf((acc[mi][ni][3] - muA[3]) * invA[3] * gr[ni] + br[ni]);
                const int c = ni * 16 + lrow;
                const int gn = gnb ^ (c & 31);
                *reinterpret_cast<ushort4*>(&kvl[c * 256 + gn * 8 + (kh & 1) * 4]) = o;
            }
        }
        __syncthreads();
        // partial scores: wave w -> local head hp = w>>2, mi-tile T = w&3.
        // S[d][e] = sum_n k[c=d][n] * v[c=e][n] over this block's 256 n (8 K-steps of 32).
        const int hp = w >> 2, T = w & 3;
        const ushort* Ak = SH + (hp * 2) * 16384;
        const ushort* Bv = SH + (hp * 2 + 1) * 16384;
        const int arow = T * 16 + lrow;
        f32x4 sacc[4] = {};
#pragma unroll
        for (int ks = 0; ks < 8; ++ks) {
            const int gnr = ks * 4 + kh;
            s16x8 afk = *reinterpret_cast<const s16x8*>(
                &Ak[arow * 256 + ((gnr ^ (arow & 31)) * 8)]);
#pragma unroll
            for (int ni = 0; ni < 4; ni++) {
                const int erow = ni * 16 + lrow;
                s16x8 bfv = *reinterpret_cast<const s16x8*>(
                    &Bv[erow * 256 + ((gnr ^ (erow & 31)) * 8)]);
                sacc[ni] = __builtin_amdgcn_mfma_f32_16x16x32_bf16(afk, bfv, sacc[ni], 0, 0, 0);
            }
        }
        const int bh = (m0 >> 12) * 16 + i_nb * 2 + hp;
        float* scb = scp + (size_t)bh * 4096;
        const float scale = 1.f / 4096.f;
#pragma unroll
        for (int ni = 0; ni < 4; ni++)
#pragma unroll
            for (int j = 0; j < 4; j++) {
                const int d = T * 16 + kh * 4 + j;
                const int e = ni * 16 + lrow;
                atomicAdd(&scb[d * 64 + e], sacc[ni][j] * scale);
            }
    } else {
#pragma unroll
        for (int mi = 0; mi < 8; mi++)
#pragma unroll
            for (int ni = 0; ni < 4; ni++) {
                int e = n0 + wc * 64 + ni * 16 + lrow;
                float bv2 = bias[e];
#pragma unroll
                for (int j = 0; j < 4; j++) {
                    int m = m0 + wr * 128 + mi * 16 + kh * 4 + j;
                    outf[(size_t)m * Nn + e] = acc[mi][ni][j] + bv2;
                }
            }
    }
}

// ---------------- fold GEMM (128x128 tile, full grid): fT[m][c] = sum_d A[m][d]*Bt[c][d] ------------
// Round-8-verified 3-slot ring, BK=32, counted vmcnt(8), granule-XOR swizzle. M=4096, Nn=1024, K=1024.
__global__ __launch_bounds__(256) void fold_k(const ushort* __restrict__ A,
                                              const ushort* __restrict__ Bt,
                                              ushort* __restrict__ out)
{
    __shared__ __align__(16) ushort SH2[24576];
    const int t = threadIdx.x;
    const int w = t >> 6, lane = t & 63;
    const int wm = w >> 1, wn = w & 1;
    const int lrow = lane & 15, kh = lane >> 4;
    const int n0 = blockIdx.x * 128, m0 = blockIdx.y * 128;

    const int srow0 = w * 32 + (lane >> 2);
    const int scolSwz = (((lane & 3) ^ ((lane >> 3) & 3)) * 8);

    f32x4 acc[4][4] = {};

    auto STAGE = [&](int kt, int s) {
        ushort* As = SH2 + s * 8192;
        ushort* Bs = As + 4096;
        const ushort* Ag = A  + (size_t)(m0 + srow0) * 1024 + kt * 32 + scolSwz;
        const ushort* Bg = Bt + (size_t)(n0 + srow0) * 1024 + kt * 32 + scolSwz;
        gload_lds16(Ag,             As + w * 1024);
        gload_lds16(Bg,             Bs + w * 1024);
        gload_lds16(Ag + 16 * 1024, As + w * 1024 + 512);
        gload_lds16(Bg + 16 * 1024, Bs + w * 1024 + 512);
    };

    const int rdoff = (kh ^ ((lrow >> 1) & 3)) * 8;

    auto COMPUTE = [&](int s) {
        const ushort* As = SH2 + s * 8192;
        const ushort* Bs = As + 4096;
        s16x8 af[4], bfr[4];
#pragma unroll
        for (int mi = 0; mi < 4; mi++)
            af[mi] = *reinterpret_cast<const s16x8*>(&As[(wm * 64 + mi * 16 + lrow) * 32 + rdoff]);
#pragma unroll
        for (int ni = 0; ni < 4; ni++)
            bfr[ni] = *reinterpret_cast<const s16x8*>(&Bs[(wn * 64 + ni * 16 + lrow) * 32 + rdoff]);
#pragma unroll
        for (int mi = 0; mi < 4; mi++)
#pragma unroll
            for (int ni = 0; ni < 4; ni++)
                acc[mi][ni] = __builtin_amdgcn_mfma_f32_16x16x32_bf16(af[mi], bfr[ni], acc[mi][ni], 0, 0, 0);
    };

    STAGE(0, 0);
    STAGE(1, 1);
    int ss = 2, sc_ = 0;
    for (int kt = 0; kt < 30; ++kt) {
        STAGE(kt + 2, ss);
        ss = (ss == 2) ? 0 : ss + 1;
        WAITVM(8);
        FULLBAR();
        COMPUTE(sc_);
        sc_ = (sc_ == 2) ? 0 : sc_ + 1;
        FULLBAR();
    }
    WAITVM(4); FULLBAR(); COMPUTE(0); FULLBAR();
    WAITVM(0); FULLBAR(); COMPUTE(1);

#pragma unroll
    for (int mi = 0; mi < 4; mi++)
#pragma unroll
        for (int ni = 0; ni < 4; ni++) {
            int e = n0 + wn * 64 + ni * 16 + lrow;
#pragma unroll
            for (int j = 0; j < 4; j++) {
                int m = m0 + wm * 64 + mi * 16 + kh * 4 + j;
                out[(size_t)m * 1024 + e] = f2bf(acc[mi][ni][j]);
            }
        }
}

// -------- W'T[b][f][h*64+d] = sum_e woutT[f][h*64+e] * sc[b*16+h][d][e], bf16 out --------
__global__ __launch_bounds__(256) void wprime_k(const float* __restrict__ sc,
                                                const ushort* __restrict__ woutT,
                                                ushort* __restrict__ wpT)
{
    __shared__ float scl[64][65];      // [e][d], padded
    __shared__ ushort wl[128][72];     // [f_local][e], padded
    int bh = blockIdx.y;
    int b = bh >> 4, h = bh & 15;
    int f0 = blockIdx.x * 128;
    int t = threadIdx.x;
    for (int i = t; i < 4096; i += 256) {
        int d2 = i >> 6, e = i & 63;
        scl[e][d2] = sc[(size_t)bh * 4096 + i];
    }
    for (int i = t; i < 1024; i += 256) {
        int fl = i >> 3, c = i & 7;
        *reinterpret_cast<int4*>(&wl[fl][c * 8]) =
            *reinterpret_cast<const int4*>(woutT + (size_t)(f0 + fl) * 1024 + h * 64 + c * 8);
    }
    __syncthreads();
    int dd = (t & 7) * 8;
    int fl0 = t >> 3;
#pragma unroll
    for (int fi = 0; fi < 4; ++fi) {
        int fl = fi * 32 + fl0;
        float acc[8] = {};
        for (int e = 0; e < 64; ++e) {
            float wv = bf2f(wl[fl][e]);
#pragma unroll
            for (int i = 0; i < 8; ++i)
                acc[i] = fmaf(wv, scl[e][dd + i], acc[i]);
        }
        ushort4 o0, o1;
        o0.x = f2bf(acc[0]); o0.y = f2bf(acc[1]); o0.z = f2bf(acc[2]); o0.w = f2bf(acc[3]);
        o1.x = f2bf(acc[4]); o1.y = f2bf(acc[5]); o1.z = f2bf(acc[6]); o1.w = f2bf(acc[7]);
        ushort* op = wpT + ((size_t)b * 1024 + f0 + fl) * 1024 + h * 64 + dd;
        *reinterpret_cast<ushort4*>(op) = o0;
        *reinterpret_cast<ushort4*>(op + 4) = o1;
    }
}

extern "C" void kernel_launch(void* const* d_in, const int* in_sizes, int n_in,
                              void* d_out, int out_size, void* d_ws, size_t ws_size,
                              hipStream_t stream)
{
    const float* x       = (const float*)d_in[0];
    const float* w_qkv   = (const float*)d_in[1];
    const float* gamma_k = (const float*)d_in[2];
    const float* beta_k  = (const float*)d_in[3];
    const float* gamma_v = (const float*)d_in[4];
    const float* beta_v  = (const float*)d_in[5];
    const float* w_out   = (const float*)d_in[6];
    const float* b_out   = (const float*)d_in[7];
    float* out = (float*)d_out;

    char* ws = (char*)d_ws;
    const size_t MB = 1024 * 1024;
    ushort* xb    = (ushort*)(ws);               // 32MB [m][1024] (alive through GEMM2)
    ushort* wkvT  = (ushort*)(ws + 32 * MB);     // 4MB  [2048][1024] interleaved k/v transposed
    ushort* woutT = (ushort*)(ws + 38 * MB);     // 2MB  [1024][1024]
    ushort* wqb   = (ushort*)(ws + 40 * MB);     // 2MB  [c][1024] (q cols of w_qkv, row-major)
    float*  sc    = (float*)(ws + 48 * MB);      // 1MB  [bh][d][e]
    ushort* wpT   = (ushort*)(ws + 56 * MB);     // 8MB  [b][f][h*64+d] == flat [4096][1024]
    ushort* fT    = (ushort*)(ws + 64 * MB);     // 8MB  [b][f][c] == flat [4096][1024]

    hipMemsetAsync(sc, 0, 64 * 4096 * sizeof(float), stream);
    prep_k<<<dim3(640, 32), dim3(32, 8), 0, stream>>>(x, w_qkv, w_out, xb, wqb, wkvT, woutT);
    // GEMM1: k,v + fused LN + fused partial-scores (atomics into sc). No k/v round-trip.
    gemm_bt_k<0><<<dim3(8, 64), 512, 0, stream>>>(xb, wkvT, 2048, 0,
                                                  sc,
                                                  gamma_k, beta_k, gamma_v, beta_v,
                                                  nullptr, nullptr);
    wprime_k<<<dim3(8, 64), 256, 0, stream>>>(sc, woutT, wpT);
    // fold (flat-M batched, 128^2 tile, 256 blocks): fT[m][c] = sum_d wpT[m][d] * wqb[c][d]
    fold_k<<<dim3(8, 32), 256, 0, stream>>>(wpT, wqb, fT);
    // GEMM2: out = xb · fT(b)^T + bias
    gemm_bt_k<1><<<dim3(4, 64), 512, 0, stream>>>(xb, fT, 1024, (size_t)1048576,
                                                  nullptr,
                                                  nullptr, nullptr, nullptr, nullptr,
                                                  b_out, out);
}

// Round 18
// 188.473 us; speedup vs baseline: 1.2693x; 1.0221x over previous
//
#include <hip/hip_runtime.h>

typedef __attribute__((ext_vector_type(4))) float f32x4;
typedef __attribute__((ext_vector_type(8))) short s16x8;

#define DEV static __device__ __forceinline__

typedef __attribute__((address_space(3))) void lds_t;
typedef __attribute__((address_space(1))) void gbl_t;

DEV void gload_lds16(const void* g, void* l) {
    __builtin_amdgcn_global_load_lds((gbl_t*)g, (lds_t*)l, 16, 0, 0);
}

DEV ushort f2bf(float f) {
    unsigned u = __float_as_uint(f);
    u += 0x7fffu + ((u >> 16) & 1u);   // round-to-nearest-even
    return (ushort)(u >> 16);
}
DEV float bf2f(ushort h) { return __uint_as_float(((unsigned)h) << 16); }

// raw barrier with compiler+scheduler fences (no vmcnt(0) drain, unlike __syncthreads)
#define FULLBAR() do {                              \
    __builtin_amdgcn_sched_barrier(0);              \
    asm volatile("" ::: "memory");                  \
    __builtin_amdgcn_s_barrier();                   \
    asm volatile("" ::: "memory");                  \
    __builtin_amdgcn_sched_barrier(0);              \
} while (0)

#define WAITVM(n) asm volatile("s_waitcnt vmcnt(" #n ")" ::: "memory")
#define LGKM0() asm volatile("s_waitcnt lgkmcnt(0)" ::: "memory")

// ------------- unified prep: x-pack + weight transposes/packs + sc zero, one dispatch --------------
// bx <  64 : trans_pack_kv -> wkvT [2048][1024] (k/v cols interleaved [k_h,v_h,k_h+1,v_h+1]/256)
// bx <  96 : trans_pack woutT [1024][1024]
// bx < 128 : pack_wq -> wqb [c][1024] (q cols of w_qkv, row-major)
// bx < 640 : pack x fp32 -> bf16 xb [16384][1024]
// bx >=640 : zero sc (8x32 blocks x 256 thr x 1 float4 = 1 MB exactly)
__global__ void prep_k(const float* __restrict__ x, const float* __restrict__ wqkv,
                       const float* __restrict__ wout,
                       ushort* __restrict__ xb, ushort* __restrict__ wqb,
                       ushort* __restrict__ wkvT, ushort* __restrict__ woutT,
                       float* __restrict__ sc) {
    __shared__ float tile[32][33];
    const int bx = blockIdx.x, by = blockIdx.y;
    const int tx = threadIdx.x, ty = threadIdx.y;   // (32, 8)
    if (bx < 64) {
        int bxo = bx * 32, byr = by * 32;
        int blk = bxo >> 8, grp = (bxo >> 6) & 3, d0 = bxo & 63;
        int h = blk * 2 + (grp >> 1);
        int src = 1024 + (grp & 1) * 1024 + h * 64 + d0;
#pragma unroll
        for (int i = 0; i < 32; i += 8)
            tile[ty + i][tx] = wqkv[(size_t)(byr + ty + i) * 3072 + src + tx];
        __syncthreads();
#pragma unroll
        for (int i = 0; i < 32; i += 8)
            wkvT[(size_t)(bxo + ty + i) * 1024 + byr + tx] = f2bf(tile[tx][ty + i]);
    } else if (bx < 96) {
        int bxo = (bx - 64) * 32, byr = by * 32;
#pragma unroll
        for (int i = 0; i < 32; i += 8)
            tile[ty + i][tx] = wout[(size_t)(byr + ty + i) * 1024 + bxo + tx];
        __syncthreads();
#pragma unroll
        for (int i = 0; i < 32; i += 8)
            woutT[(size_t)(bxo + ty + i) * 1024 + byr + tx] = f2bf(tile[tx][ty + i]);
    } else if (bx < 128) {
        int t = ty * 32 + tx;
        int i = ((bx - 96) * 32 + by) * 256 + t;    // 0 .. 262143
        int r = i >> 8, c4 = i & 255;
        float4 v = *reinterpret_cast<const float4*>(wqkv + (size_t)r * 3072 + c4 * 4);
        ushort4 u;
        u.x = f2bf(v.x); u.y = f2bf(v.y); u.z = f2bf(v.z); u.w = f2bf(v.w);
        *reinterpret_cast<ushort4*>(wqb + (size_t)r * 1024 + c4 * 4) = u;
    } else if (bx < 640) {
        int t = ty * 32 + tx;
        int i = ((bx - 128) * 32 + by) * 256 + t;   // 0 .. 4194303 float4-groups
        float4 v = reinterpret_cast<const float4*>(x)[i];
        ushort4 u;
        u.x = f2bf(v.x); u.y = f2bf(v.y); u.z = f2bf(v.z); u.w = f2bf(v.w);
        reinterpret_cast<ushort4*>(xb)[i] = u;
    } else {
        int t = ty * 32 + tx;
        int i = ((bx - 640) * 32 + by) * 256 + t;   // 0 .. 65535 float4-groups (1 MB)
        float4 z = {0.f, 0.f, 0.f, 0.f};
        reinterpret_cast<float4*>(sc)[i] = z;
    }
}

// ---------------- main GEMM: C[M][Nn] = A[M][K=1024](bf16) * Bt[Nn][1024]^T (bf16), fp32 acc --------
// 256x256 block tile, 512 threads (8 waves 2M x 4N), per-wave 128x64, BK=64 (16 K-tiles),
// 2-slot LDS double buffer (128 KB), barrier-lean schedule (2 barriers/K-tile, counted vmcnt).
// MODE 0: B = interleaved wkvT ([k_h,v_h,k_h+1,v_h+1] per 256 cols). Epilogue: fused per-head
//   LayerNorm -> LN'd k,v tiles into (dead) staging LDS [4 grp][64 c][256 n] (granule-XOR,
//   ushort4-vectorized writes) -> partial scores S_h = k^T v over this block's 256 n ->
//   fp32 atomicAdd into sc[bh][d][e].  NO k/v global round-trip.
// MODE 1: add bias, write fp32 to outf[M][Nn]; Bt selected per-b via b_stride (b = m0>>12).
template <int MODE>
__global__ __launch_bounds__(512, 1) void gemm_bt_k(
    const ushort* __restrict__ A, const ushort* __restrict__ Bt,
    int Nn, size_t b_stride,
    float* __restrict__ scp,
    const float* __restrict__ gk, const float* __restrict__ bk,
    const float* __restrict__ gv, const float* __restrict__ bv,
    const float* __restrict__ bias, float* __restrict__ outf)
{
    // 2 slots x (A 256x64 + B 256x64) ushorts = 128 KB; MODE-0 kv buffer overlays exactly.
    __shared__ __align__(16) ushort SH[65536];
    const int t = threadIdx.x;
    const int w = t >> 6, lane = t & 63;
    const int wr = w >> 2, wc = w & 3;          // wave grid 2M x 4N
    const int lrow = lane & 15, kh = lane >> 4;

    // bijective XCD-chunked swizzle (grid total % 8 == 0)
    int bid = blockIdx.y * gridDim.x + blockIdx.x;
    int C8 = (gridDim.x * gridDim.y) >> 3;
    int nid = (bid & 7) * C8 + (bid >> 3);
    int n0 = (nid % gridDim.x) * 256;
    int m0 = (nid / gridDim.x) * 256;

    const ushort* Bte = (MODE == 1) ? Bt + (size_t)(m0 >> 12) * b_stride : Bt;

    // staging: half h, call c covers rows h*128 + c*64 + w*8 + (lane>>3); source pre-swizzled
    const int srow8 = w * 8 + (lane >> 3);
    const int scol = ((lane & 7) ^ ((lane >> 3) & 7)) * 8;

    // read granule offsets (ushorts): g' = (kk*4+kh) ^ (lrow&7), per-lane constants
    const int g0 = ((kh) ^ (lrow & 7)) * 8;
    const int g1 = ((4 + kh) ^ (lrow & 7)) * 8;

    f32x4 acc[8][4] = {};
    s16x8 bfr[4][2];
    s16x8 af[8];

    auto STAGE_A = [&](int kt, int s, int h) {
        ushort* As = SH + s * 32768;
        const ushort* Ag = A + (size_t)(m0 + h * 128 + srow8) * 1024 + kt * 64 + scol;
        gload_lds16(Ag,                     As + (h * 128 + w * 8) * 64);
        gload_lds16(Ag + (size_t)64 * 1024, As + (h * 128 + 64 + w * 8) * 64);
    };
    auto STAGE_B = [&](int kt, int s, int h) {
        ushort* Bs = SH + s * 32768 + 16384;
        const ushort* Bg = Bte + (size_t)(n0 + h * 128 + srow8) * 1024 + kt * 64 + scol;
        gload_lds16(Bg,                     Bs + (h * 128 + w * 8) * 64);
        gload_lds16(Bg + (size_t)64 * 1024, Bs + (h * 128 + 64 + w * 8) * 64);
    };

    // prologue: tile0 (A+B) + tile1's B halves = 12 loads
    STAGE_A(0, 0, 0); STAGE_A(0, 0, 1);
    STAGE_B(0, 0, 0); STAGE_B(0, 0, 1);
    STAGE_B(1, 1, 0); STAGE_B(1, 1, 1);

    for (int kt = 0; kt < 16; ++kt) {
        const int p = kt & 1, q = p ^ 1;
        const ushort* As = SH + p * 32768;
        const ushort* Bs = As + 16384;

        if (kt < 15) { WAITVM(4); } else { WAITVM(0); }
        FULLBAR();                          // tile kt fully landed for all waves

        // issue all B reads (both kk) and A kk0 reads; stage A(kt+1) into other buf
#pragma unroll
        for (int ni = 0; ni < 4; ni++) {
            const int r = (wc * 64 + ni * 16 + lrow) * 64;
            bfr[ni][0] = *reinterpret_cast<const s16x8*>(&Bs[r + g0]);
            bfr[ni][1] = *reinterpret_cast<const s16x8*>(&Bs[r + g1]);
        }
#pragma unroll
        for (int mi = 0; mi < 8; mi++)
            af[mi] = *reinterpret_cast<const s16x8*>(&As[(wr * 128 + mi * 16 + lrow) * 64 + g0]);
        if (kt + 1 < 16) { STAGE_A(kt + 1, q, 0); STAGE_A(kt + 1, q, 1); }

        __builtin_amdgcn_s_setprio(1);
#pragma unroll
        for (int mi = 0; mi < 8; mi++)
#pragma unroll
            for (int ni = 0; ni < 4; ni++)
                acc[mi][ni] = __builtin_amdgcn_mfma_f32_16x16x32_bf16(af[mi], bfr[ni][0], acc[mi][ni], 0, 0, 0);
        __builtin_amdgcn_s_setprio(0);

        LGKM0();                            // all my ds_reads (incl. bfr[..][1]) complete
        FULLBAR();                          // => all waves' B(kt) reads complete

        // stage B(kt+2) into same buf's B region (now provably dead); A kk1 reads
        if (kt + 2 < 16) { STAGE_B(kt + 2, p, 0); STAGE_B(kt + 2, p, 1); }
#pragma unroll
        for (int mi = 0; mi < 8; mi++)
            af[mi] = *reinterpret_cast<const s16x8*>(&As[(wr * 128 + mi * 16 + lrow) * 64 + g1]);

        __builtin_amdgcn_s_setprio(1);
#pragma unroll
        for (int mi = 0; mi < 8; mi++)
#pragma unroll
            for (int ni = 0; ni < 4; ni++)
                acc[mi][ni] = __builtin_amdgcn_mfma_f32_16x16x32_bf16(af[mi], bfr[ni][1], acc[mi][ni], 0, 0, 0);
        __builtin_amdgcn_s_setprio(0);
    }

    // C/D layout (verified m89): col = lane&15, row = (lane>>4)*4 + reg
    if (MODE == 0) {
        // this wave's 64-col group: n0 block covers heads 2i, 2i+1 as [k,v,k,v]
        const int i_nb = n0 >> 8;
        const int h = i_nb * 2 + (wc >> 1);
        const int is_k = ((wc & 1) == 0);
        const float* g  = is_k ? gk : gv;
        const float* bb = is_k ? bk : bv;
        float gr[4], br[4];
#pragma unroll
        for (int ni = 0; ni < 4; ni++) {
            gr[ni] = g[h * 64 + ni * 16 + lrow];
            br[ni] = bb[h * 64 + ni * 16 + lrow];
        }
        __syncthreads();                    // staging LDS dead for ALL waves; kv buffer overlays
        // write LN'd values into group wc: [64 c][256 n], 8-ushort granules XOR'd by (c&31).
        // For fixed (mi,ni) the 4 j-values are contiguous ushorts (n&7 = (kh&1)*4+j) -> ushort4.
        ushort* kvl = SH + wc * 16384;
#pragma unroll
        for (int mi = 0; mi < 8; mi++) {
            float muA[4], invA[4];
#pragma unroll
            for (int j = 0; j < 4; j++) {
                float s = acc[mi][0][j] + acc[mi][1][j] + acc[mi][2][j] + acc[mi][3][j];
                s += __shfl_xor(s, 1, 64);
                s += __shfl_xor(s, 2, 64);
                s += __shfl_xor(s, 4, 64);
                s += __shfl_xor(s, 8, 64);
                float mu = s * (1.f / 64.f);
                float t2 = 0.f;
#pragma unroll
                for (int ni = 0; ni < 4; ni++) {
                    float dd = acc[mi][ni][j] - mu;
                    t2 += dd * dd;
                }
                t2 += __shfl_xor(t2, 1, 64);
                t2 += __shfl_xor(t2, 2, 64);
                t2 += __shfl_xor(t2, 4, 64);
                t2 += __shfl_xor(t2, 8, 64);
                muA[j] = mu;
                invA[j] = rsqrtf(t2 * (1.f / 64.f) + 1e-5f);
            }
            const int nbase = wr * 128 + mi * 16 + kh * 4;   // nbase%4==0; n>>3 const over j
            const int gnb = nbase >> 3;
#pragma unroll
            for (int ni = 0; ni < 4; ni++) {
                ushort4 o;
                o.x = f2bf((acc[mi][ni][0] - muA[0]) * invA[0] * gr[ni] + br[ni]);
                o.y = f2bf((acc[mi][ni][1] - muA[1]) * invA[1] * gr[ni] + br[ni]);
                o.z = f2bf((acc[mi][ni][2] - muA[2]) * invA[2] * gr[ni] + br[ni]);
                o.w = f2bf((acc[mi][ni][3] - muA[3]) * invA[3] * gr[ni] + br[ni]);
                const int c = ni * 16 + lrow;
                const int gn = gnb ^ (c & 31);
                *reinterpret_cast<ushort4*>(&kvl[c * 256 + gn * 8 + (kh & 1) * 4]) = o;
            }
        }
        __syncthreads();
        // partial scores: wave w -> local head hp = w>>2, mi-tile T = w&3.
        // S[d][e] = sum_n k[c=d][n] * v[c=e][n] over this block's 256 n (8 K-steps of 32).
        const int hp = w >> 2, T = w & 3;
        const ushort* Ak = SH + (hp * 2) * 16384;
        const ushort* Bv = SH + (hp * 2 + 1) * 16384;
        const int arow = T * 16 + lrow;
        f32x4 sacc[4] = {};
#pragma unroll
        for (int ks = 0; ks < 8; ++ks) {
            const int gnr = ks * 4 + kh;
            s16x8 afk = *reinterpret_cast<const s16x8*>(
                &Ak[arow * 256 + ((gnr ^ (arow & 31)) * 8)]);
#pragma unroll
            for (int ni = 0; ni < 4; ni++) {
                const int erow = ni * 16 + lrow;
                s16x8 bfv = *reinterpret_cast<const s16x8*>(
                    &Bv[erow * 256 + ((gnr ^ (erow & 31)) * 8)]);
                sacc[ni] = __builtin_amdgcn_mfma_f32_16x16x32_bf16(afk, bfv, sacc[ni], 0, 0, 0);
            }
        }
        const int bh = (m0 >> 12) * 16 + i_nb * 2 + hp;
        float* scb = scp + (size_t)bh * 4096;
        const float scale = 1.f / 4096.f;
#pragma unroll
        for (int ni = 0; ni < 4; ni++)
#pragma unroll
            for (int j = 0; j < 4; j++) {
                const int d = T * 16 + kh * 4 + j;
                const int e = ni * 16 + lrow;
                atomicAdd(&scb[d * 64 + e], sacc[ni][j] * scale);
            }
    } else {
#pragma unroll
        for (int mi = 0; mi < 8; mi++)
#pragma unroll
            for (int ni = 0; ni < 4; ni++) {
                int e = n0 + wc * 64 + ni * 16 + lrow;
                float bv2 = bias[e];
#pragma unroll
                for (int j = 0; j < 4; j++) {
                    int m = m0 + wr * 128 + mi * 16 + kh * 4 + j;
                    outf[(size_t)m * Nn + e] = acc[mi][ni][j] + bv2;
                }
            }
    }
}

// ---------------- fold GEMM (128x128 tile, full grid): fT[m][c] = sum_d A[m][d]*Bt[c][d] ------------
// Round-8-verified 3-slot ring, BK=32, counted vmcnt(8), granule-XOR swizzle. M=4096, Nn=1024, K=1024.
__global__ __launch_bounds__(256) void fold_k(const ushort* __restrict__ A,
                                              const ushort* __restrict__ Bt,
                                              ushort* __restrict__ out)
{
    __shared__ __align__(16) ushort SH2[24576];
    const int t = threadIdx.x;
    const int w = t >> 6, lane = t & 63;
    const int wm = w >> 1, wn = w & 1;
    const int lrow = lane & 15, kh = lane >> 4;
    const int n0 = blockIdx.x * 128, m0 = blockIdx.y * 128;

    const int srow0 = w * 32 + (lane >> 2);
    const int scolSwz = (((lane & 3) ^ ((lane >> 3) & 3)) * 8);

    f32x4 acc[4][4] = {};

    auto STAGE = [&](int kt, int s) {
        ushort* As = SH2 + s * 8192;
        ushort* Bs = As + 4096;
        const ushort* Ag = A  + (size_t)(m0 + srow0) * 1024 + kt * 32 + scolSwz;
        const ushort* Bg = Bt + (size_t)(n0 + srow0) * 1024 + kt * 32 + scolSwz;
        gload_lds16(Ag,             As + w * 1024);
        gload_lds16(Bg,             Bs + w * 1024);
        gload_lds16(Ag + 16 * 1024, As + w * 1024 + 512);
        gload_lds16(Bg + 16 * 1024, Bs + w * 1024 + 512);
    };

    const int rdoff = (kh ^ ((lrow >> 1) & 3)) * 8;

    auto COMPUTE = [&](int s) {
        const ushort* As = SH2 + s * 8192;
        const ushort* Bs = As + 4096;
        s16x8 af[4], bfr[4];
#pragma unroll
        for (int mi = 0; mi < 4; mi++)
            af[mi] = *reinterpret_cast<const s16x8*>(&As[(wm * 64 + mi * 16 + lrow) * 32 + rdoff]);
#pragma unroll
        for (int ni = 0; ni < 4; ni++)
            bfr[ni] = *reinterpret_cast<const s16x8*>(&Bs[(wn * 64 + ni * 16 + lrow) * 32 + rdoff]);
#pragma unroll
        for (int mi = 0; mi < 4; mi++)
#pragma unroll
            for (int ni = 0; ni < 4; ni++)
                acc[mi][ni] = __builtin_amdgcn_mfma_f32_16x16x32_bf16(af[mi], bfr[ni], acc[mi][ni], 0, 0, 0);
    };

    STAGE(0, 0);
    STAGE(1, 1);
    int ss = 2, sc_ = 0;
    for (int kt = 0; kt < 30; ++kt) {
        STAGE(kt + 2, ss);
        ss = (ss == 2) ? 0 : ss + 1;
        WAITVM(8);
        FULLBAR();
        COMPUTE(sc_);
        sc_ = (sc_ == 2) ? 0 : sc_ + 1;
        FULLBAR();
    }
    WAITVM(4); FULLBAR(); COMPUTE(0); FULLBAR();
    WAITVM(0); FULLBAR(); COMPUTE(1);

#pragma unroll
    for (int mi = 0; mi < 4; mi++)
#pragma unroll
        for (int ni = 0; ni < 4; ni++) {
            int e = n0 + wn * 64 + ni * 16 + lrow;
#pragma unroll
            for (int j = 0; j < 4; j++) {
                int m = m0 + wm * 64 + mi * 16 + kh * 4 + j;
                out[(size_t)m * 1024 + e] = f2bf(acc[mi][ni][j]);
            }
        }
}

// -------- W'T[b][f][h*64+d] = sum_e woutT[f][h*64+e] * sc[b*16+h][d][e], bf16 out --------
__global__ __launch_bounds__(256) void wprime_k(const float* __restrict__ sc,
                                                const ushort* __restrict__ woutT,
                                                ushort* __restrict__ wpT)
{
    __shared__ float scl[64][65];      // [e][d], padded
    __shared__ ushort wl[128][72];     // [f_local][e], padded
    int bh = blockIdx.y;
    int b = bh >> 4, h = bh & 15;
    int f0 = blockIdx.x * 128;
    int t = threadIdx.x;
    for (int i = t; i < 4096; i += 256) {
        int d2 = i >> 6, e = i & 63;
        scl[e][d2] = sc[(size_t)bh * 4096 + i];
    }
    for (int i = t; i < 1024; i += 256) {
        int fl = i >> 3, c = i & 7;
        *reinterpret_cast<int4*>(&wl[fl][c * 8]) =
            *reinterpret_cast<const int4*>(woutT + (size_t)(f0 + fl) * 1024 + h * 64 + c * 8);
    }
    __syncthreads();
    int dd = (t & 7) * 8;
    int fl0 = t >> 3;
#pragma unroll
    for (int fi = 0; fi < 4; ++fi) {
        int fl = fi * 32 + fl0;
        float acc[8] = {};
        for (int e = 0; e < 64; ++e) {
            float wv = bf2f(wl[fl][e]);
#pragma unroll
            for (int i = 0; i < 8; ++i)
                acc[i] = fmaf(wv, scl[e][dd + i], acc[i]);
        }
        ushort4 o0, o1;
        o0.x = f2bf(acc[0]); o0.y = f2bf(acc[1]); o0.z = f2bf(acc[2]); o0.w = f2bf(acc[3]);
        o1.x = f2bf(acc[4]); o1.y = f2bf(acc[5]); o1.z = f2bf(acc[6]); o1.w = f2bf(acc[7]);
        ushort* op = wpT + ((size_t)b * 1024 + f0 + fl) * 1024 + h * 64 + dd;
        *reinterpret_cast<ushort4*>(op) = o0;
        *reinterpret_cast<ushort4*>(op + 4) = o1;
    }
}

extern "C" void kernel_launch(void* const* d_in, const int* in_sizes, int n_in,
                              void* d_out, int out_size, void* d_ws, size_t ws_size,
                              hipStream_t stream)
{
    const float* x       = (const float*)d_in[0];
    const float* w_qkv   = (const float*)d_in[1];
    const float* gamma_k = (const float*)d_in[2];
    const float* beta_k  = (const float*)d_in[3];
    const float* gamma_v = (const float*)d_in[4];
    const float* beta_v  = (const float*)d_in[5];
    const float* w_out   = (const float*)d_in[6];
    const float* b_out   = (const float*)d_in[7];
    float* out = (float*)d_out;

    char* ws = (char*)d_ws;
    const size_t MB = 1024 * 1024;
    ushort* xb    = (ushort*)(ws);               // 32MB [m][1024] (alive through GEMM2)
    ushort* wkvT  = (ushort*)(ws + 32 * MB);     // 4MB  [2048][1024] interleaved k/v transposed
    ushort* woutT = (ushort*)(ws + 38 * MB);     // 2MB  [1024][1024]
    ushort* wqb   = (ushort*)(ws + 40 * MB);     // 2MB  [c][1024] (q cols of w_qkv, row-major)
    float*  sc    = (float*)(ws + 48 * MB);      // 1MB  [bh][d][e]
    ushort* wpT   = (ushort*)(ws + 56 * MB);     // 8MB  [b][f][h*64+d] == flat [4096][1024]
    ushort* fT    = (ushort*)(ws + 64 * MB);     // 8MB  [b][f][c] == flat [4096][1024]

    // prep: x-pack + weight packs + sc zero, one dispatch
    prep_k<<<dim3(648, 32), dim3(32, 8), 0, stream>>>(x, w_qkv, w_out, xb, wqb, wkvT, woutT, sc);
    // GEMM1: k,v + fused LN + fused partial-scores (atomics into sc). No k/v round-trip.
    gemm_bt_k<0><<<dim3(8, 64), 512, 0, stream>>>(xb, wkvT, 2048, 0,
                                                  sc,
                                                  gamma_k, beta_k, gamma_v, beta_v,
                                                  nullptr, nullptr);
    wprime_k<<<dim3(8, 64), 256, 0, stream>>>(sc, woutT, wpT);
    // fold (flat-M batched, 128^2 tile, 256 blocks): fT[m][c] = sum_d wpT[m][d] * wqb[c][d]
    fold_k<<<dim3(8, 32), 256, 0, stream>>>(wpT, wqb, fT);
    // GEMM2: out = xb · fT(b)^T + bias
    gemm_bt_k<1><<<dim3(4, 64), 512, 0, stream>>>(xb, fT, 1024, (size_t)1048576,
                                                  nullptr,
                                                  nullptr, nullptr, nullptr, nullptr,
                                                  b_out, out);
}